// Round 1
// baseline (1480.887 us; speedup 1.0000x reference)
//
#include <hip/hip_runtime.h>

#define SDIM 1024
#define HNUM 8
#define DDIM 64
#define EMBD 512
#define NBATCH 8

static constexpr float SCALE = 0.044194173824159216f; // 1/sqrt(512)

// ---------------------------------------------------------------------------
// Kernel A: per-head projections  vals/keys/qrs[n,s,h,:] = x[n,s,h,:] @ W.T + b
// ---------------------------------------------------------------------------
__global__ __launch_bounds__(256) void proj_kernel(
    const float* __restrict__ v, const float* __restrict__ k, const float* __restrict__ q,
    const float* __restrict__ Wv, const float* __restrict__ bv,
    const float* __restrict__ Wk, const float* __restrict__ bk,
    const float* __restrict__ Wq, const float* __restrict__ bq,
    float* __restrict__ vals, float* __restrict__ keys, float* __restrict__ qrs)
{
    __shared__ float xs[3][EMBD];            // token's v,k,q rows
    __shared__ float Ws[3][DDIM][DDIM + 1];  // padded: bank-conflict-free

    const int tok = blockIdx.x;  // n*S + s
    const int t = threadIdx.x;

    for (int e = t; e < 3 * DDIM * DDIM; e += 256) {
        const int m = e >> 12, r = (e >> 6) & 63, c = e & 63;
        const float* Wm = (m == 0) ? Wv : (m == 1) ? Wk : Wq;
        Ws[m][r][c] = Wm[r * DDIM + c];
    }
    for (int e = t; e < 3 * EMBD; e += 256) {
        const int m = e >> 9, c = e & 511;
        const float* xm = (m == 0) ? v : (m == 1) ? k : q;
        xs[m][c] = xm[tok * EMBD + c];
    }
    __syncthreads();

    const int d = t & 63;
    const int hq = t >> 6;  // 0..3
    for (int m = 0; m < 3; ++m) {
        const float* bm = (m == 0) ? bv : (m == 1) ? bk : bq;
        float* om = (m == 0) ? vals : (m == 1) ? keys : qrs;
        for (int hh = hq; hh < HNUM; hh += 4) {
            float acc = bm[d];
            #pragma unroll 8
            for (int dd = 0; dd < DDIM; ++dd)
                acc += xs[m][hh * DDIM + dd] * Ws[m][d][dd];
            om[(tok * HNUM + hh) * DDIM + d] = acc;
        }
    }
}

// ---------------------------------------------------------------------------
// Wo transpose (for coalesced B-reads in out_kernel)
// ---------------------------------------------------------------------------
__global__ __launch_bounds__(256) void transpose_wo(
    const float* __restrict__ Wo, float* __restrict__ WoT)
{
    const int id = blockIdx.x * 256 + threadIdx.x;  // EMB*EMB
    const int kk = id >> 9, c = id & 511;
    WoT[kk * EMBD + c] = Wo[c * EMBD + kk];
}

// ---------------------------------------------------------------------------
// Kernel B: fused attention.
// Block = (n, h, 64-query-row tile). For each 64-wide j-tile:
//   phase 1: per (i,j) pair one dot:
//            j>i : e = exp( (q_i.k_j) * SCALE )
//            j<=i: w = v_i . E[S-1-(i-j)]       (skewed relative-pos bias)
//   phase 2: per (i, 16-d slice): num += e*v_j, den += e (j>i); z2 += w*v_j.
// Row i==S-1 is fully masked -> softmax is uniform 1/S (all-equal -1e20).
// z = num/den + z2  (or vsum/S + z2 for the last row).
// ---------------------------------------------------------------------------
__global__ __launch_bounds__(256) void attn_kernel(
    const float* __restrict__ vals, const float* __restrict__ keys,
    const float* __restrict__ qrs, const float* __restrict__ E,
    float* __restrict__ z)
{
    __shared__ float q_s [64][68];
    __shared__ float vi_s[64][68];
    __shared__ float k_s [64][68];
    __shared__ float vj_s[64][68];
    __shared__ float E_s [127][68];  // E window rows eb .. eb+126
    __shared__ float s_s [64][65];   // per-tile coefficients

    const int blk = blockIdx.x;      // n*128 + h*16 + it
    const int it = blk & 15;
    const int h  = (blk >> 4) & 7;
    const int n  = blk >> 7;
    const int i0 = it * 64;
    const int t  = threadIdx.x;

    // stage q, v_i rows once
    {
        const int row = t >> 2, seg = t & 3;
        const int gi_ = i0 + row;
        const float4* qsrc = (const float4*)&qrs [((n * SDIM + gi_) * HNUM + h) * DDIM];
        const float4* vsrc = (const float4*)&vals[((n * SDIM + gi_) * HNUM + h) * DDIM];
        #pragma unroll
        for (int u = 0; u < 4; ++u) {
            ((float4*)&q_s [row][seg * 16])[u] = qsrc[seg * 4 + u];
            ((float4*)&vi_s[row][seg * 16])[u] = vsrc[seg * 4 + u];
        }
    }

    // phase-2 identity: thread owns (row il, d-slice dseg*16..+15)
    const int dseg = t & 3, il = t >> 2;
    const int gi = i0 + il;
    float num[16], z2a[16], vsum[16];
    float den = 0.f;
    #pragma unroll
    for (int u = 0; u < 16; ++u) { num[u] = 0.f; z2a[u] = 0.f; vsum[u] = 0.f; }

    // phase-1 identity: 4x4 microtile at (ib, jb)
    const int iq = t & 15, jq = t >> 4;
    const int ib = iq * 4, jb = jq * 4;

    for (int jt = 0; jt < 16; ++jt) {
        const int j0 = jt * 64;
        __syncthreads();  // prior phase 2 done with vj_s/s_s

        // ---- stage j-tile ----
        {
            const int row = t >> 2, seg = t & 3;
            const int gj = j0 + row;
            const float4* vsrc = (const float4*)&vals[((n * SDIM + gj) * HNUM + h) * DDIM];
            #pragma unroll
            for (int u = 0; u < 4; ++u)
                ((float4*)&vj_s[row][seg * 16])[u] = vsrc[seg * 4 + u];
            if (jt >= it) {  // tile has j>i pairs -> need keys
                const float4* ksrc = (const float4*)&keys[((n * SDIM + gj) * HNUM + h) * DDIM];
                #pragma unroll
                for (int u = 0; u < 4; ++u)
                    ((float4*)&k_s[row][seg * 16])[u] = ksrc[seg * 4 + u];
            }
            if (jt <= it) {  // tile has j<=i pairs -> need E window
                const int eb = SDIM - 1 - i0 - 63 + j0;  // always >= 0
                for (int sidx = t; sidx < 127 * 16; sidx += 256) {
                    const int er = sidx >> 4, ec = sidx & 15;
                    const int g = eb + er;
                    float4 val = make_float4(0.f, 0.f, 0.f, 0.f);
                    if (g < SDIM) val = ((const float4*)&E[g * DDIM])[ec];
                    ((float4*)&E_s[er][0])[ec] = val;
                }
            }
        }
        __syncthreads();

        // ---- phase 1: coefficients into s_s ----
        if (jt > it) {  // pure upper: exp(qk * scale)
            float acc[4][4];
            #pragma unroll
            for (int r = 0; r < 4; ++r)
                #pragma unroll
                for (int c = 0; c < 4; ++c) acc[r][c] = 0.f;
            for (int dc = 0; dc < 16; ++dc) {
                float4 a[4], b[4];
                #pragma unroll
                for (int r = 0; r < 4; ++r) a[r] = ((const float4*)&q_s[ib + r][0])[dc];
                #pragma unroll
                for (int c = 0; c < 4; ++c) b[c] = ((const float4*)&k_s[jb + c][0])[dc];
                #pragma unroll
                for (int r = 0; r < 4; ++r)
                    #pragma unroll
                    for (int c = 0; c < 4; ++c)
                        acc[r][c] += a[r].x * b[c].x + a[r].y * b[c].y
                                   + a[r].z * b[c].z + a[r].w * b[c].w;
            }
            #pragma unroll
            for (int r = 0; r < 4; ++r)
                #pragma unroll
                for (int c = 0; c < 4; ++c)
                    s_s[ib + r][jb + c] = __expf(acc[r][c] * SCALE);
        } else if (jt < it) {  // pure lower: bias dot v_i . E[...]
            float acc[4][4];
            #pragma unroll
            for (int r = 0; r < 4; ++r)
                #pragma unroll
                for (int c = 0; c < 4; ++c) acc[r][c] = 0.f;
            const int base = 63 + jb - ib;  // E_s row for (r=0,c=0); in [3,123]
            for (int dc = 0; dc < 16; ++dc) {
                float4 a[4], b[7];
                #pragma unroll
                for (int r = 0; r < 4; ++r) a[r] = ((const float4*)&vi_s[ib + r][0])[dc];
                #pragma unroll
                for (int u = 0; u < 7; ++u) b[u] = ((const float4*)&E_s[base - 3 + u][0])[dc];
                #pragma unroll
                for (int r = 0; r < 4; ++r)
                    #pragma unroll
                    for (int c = 0; c < 4; ++c) {
                        const float4 bb = b[3 + c - r];
                        acc[r][c] += a[r].x * bb.x + a[r].y * bb.y
                                   + a[r].z * bb.z + a[r].w * bb.w;
                    }
            }
            #pragma unroll
            for (int r = 0; r < 4; ++r)
                #pragma unroll
                for (int c = 0; c < 4; ++c)
                    s_s[ib + r][jb + c] = acc[r][c];
        } else {  // diagonal tile: mixed, per-pair
            #pragma unroll
            for (int r = 0; r < 4; ++r) {
                #pragma unroll
                for (int c = 0; c < 4; ++c) {
                    const int li = ib + r, lj = jb + c;
                    const bool up = (lj > li);  // j0 == i0
                    const float* arow = up ? &q_s[li][0] : &vi_s[li][0];
                    const float* brow = up ? &k_s[lj][0] : &E_s[63 + lj - li][0];
                    float acc = 0.f;
                    #pragma unroll 4
                    for (int dc = 0; dc < 16; ++dc) {
                        const float4 a = ((const float4*)arow)[dc];
                        const float4 b = ((const float4*)brow)[dc];
                        acc += a.x * b.x + a.y * b.y + a.z * b.z + a.w * b.w;
                    }
                    s_s[li][lj] = up ? __expf(acc * SCALE) : acc;
                }
            }
        }
        __syncthreads();

        // ---- phase 2: accumulate ----
        for (int j = 0; j < 64; ++j) {
            const float cc = s_s[il][j];
            const int gj = j0 + j;
            const float4* vj = (const float4*)&vj_s[j][dseg * 16];
            float wv[16];
            #pragma unroll
            for (int u4 = 0; u4 < 4; ++u4) {
                const float4 tmp = vj[u4];
                wv[u4 * 4 + 0] = tmp.x; wv[u4 * 4 + 1] = tmp.y;
                wv[u4 * 4 + 2] = tmp.z; wv[u4 * 4 + 3] = tmp.w;
            }
            if (gj > gi) {
                den += cc;
                #pragma unroll
                for (int u = 0; u < 16; ++u) num[u] += cc * wv[u];
            } else {
                #pragma unroll
                for (int u = 0; u < 16; ++u) z2a[u] += cc * wv[u];
            }
            if (gi == SDIM - 1) {  // fully-masked row: uniform softmax needs sum(v)
                #pragma unroll
                for (int u = 0; u < 16; ++u) vsum[u] += wv[u];
            }
        }
    }

    // ---- combine & write z ----
    float invd;
    if (gi == SDIM - 1) {
        invd = 1.f / (float)SDIM;
        #pragma unroll
        for (int u = 0; u < 16; ++u) num[u] = vsum[u];
    } else {
        invd = 1.f / den;
    }
    float* zp = &z[((n * SDIM + gi) * HNUM + h) * DDIM + dseg * 16];
    #pragma unroll
    for (int u4 = 0; u4 < 4; ++u4) {
        float4 o;
        o.x = num[u4 * 4 + 0] * invd + z2a[u4 * 4 + 0];
        o.y = num[u4 * 4 + 1] * invd + z2a[u4 * 4 + 1];
        o.z = num[u4 * 4 + 2] * invd + z2a[u4 * 4 + 2];
        o.w = num[u4 * 4 + 3] * invd + z2a[u4 * 4 + 3];
        ((float4*)zp)[u4] = o;
    }
}

// ---------------------------------------------------------------------------
// Kernel C: out = z @ Wo.T + bo   (reads pre-transposed WoT for coalescing)
// ---------------------------------------------------------------------------
__global__ __launch_bounds__(256) void out_kernel(
    const float* __restrict__ z, const float* __restrict__ WoT,
    const float* __restrict__ bo, float* __restrict__ out)
{
    __shared__ float z_s[16][EMBD];  // 32 KB
    const int r0 = blockIdx.x * 16;
    const int c0 = blockIdx.y * 128;
    const int t = threadIdx.x;

    for (int e = t; e < 16 * (EMBD / 4); e += 256) {
        const int row = e >> 7, col4 = e & 127;
        ((float4*)&z_s[row][0])[col4] = ((const float4*)&z[(r0 + row) * EMBD])[col4];
    }
    __syncthreads();

    const int cq = t & 31;      // 4 consecutive cols
    const int rq = t >> 5;      // 2 rows
    const int c = c0 + cq * 4;
    float4 acc0 = make_float4(0.f, 0.f, 0.f, 0.f);
    float4 acc1 = make_float4(0.f, 0.f, 0.f, 0.f);
    for (int kk = 0; kk < EMBD; ++kk) {
        const float4 b = *(const float4*)&WoT[kk * EMBD + c];
        const float a0 = z_s[rq * 2 + 0][kk];
        const float a1 = z_s[rq * 2 + 1][kk];
        acc0.x += a0 * b.x; acc0.y += a0 * b.y; acc0.z += a0 * b.z; acc0.w += a0 * b.w;
        acc1.x += a1 * b.x; acc1.y += a1 * b.y; acc1.z += a1 * b.z; acc1.w += a1 * b.w;
    }
    const float4 bb = *(const float4*)&bo[c];
    acc0.x += bb.x; acc0.y += bb.y; acc0.z += bb.z; acc0.w += bb.w;
    acc1.x += bb.x; acc1.y += bb.y; acc1.z += bb.z; acc1.w += bb.w;
    *(float4*)&out[(r0 + rq * 2 + 0) * EMBD + c] = acc0;
    *(float4*)&out[(r0 + rq * 2 + 1) * EMBD + c] = acc1;
}

// ---------------------------------------------------------------------------
extern "C" void kernel_launch(void* const* d_in, const int* in_sizes, int n_in,
                              void* d_out, int out_size, void* d_ws, size_t ws_size,
                              hipStream_t stream) {
    const float* v  = (const float*)d_in[0];
    const float* k  = (const float*)d_in[1];
    const float* q  = (const float*)d_in[2];
    const float* Wv = (const float*)d_in[3];
    const float* bv = (const float*)d_in[4];
    const float* Wk = (const float*)d_in[5];
    const float* bk = (const float*)d_in[6];
    const float* Wq = (const float*)d_in[7];
    const float* bq = (const float*)d_in[8];
    const float* E  = (const float*)d_in[9];   // (1,S,D) flat
    const float* Wo = (const float*)d_in[10];
    const float* bo = (const float*)d_in[11];
    float* out = (float*)d_out;

    // workspace layout (floats): needs ~65 MB total
    float* ws   = (float*)d_ws;
    float* vals = ws;                    //  4M floats
    float* keys = ws + 4194304;          //  4M
    float* qrs  = ws + 8388608;          //  4M
    float* zbuf = ws + 12582912;         //  4M
    float* WoT  = ws + 16777216;         //  256K

    proj_kernel<<<NBATCH * SDIM, 256, 0, stream>>>(v, k, q, Wv, bv, Wk, bk, Wq, bq,
                                                   vals, keys, qrs);
    transpose_wo<<<(EMBD * EMBD) / 256, 256, 0, stream>>>(Wo, WoT);
    attn_kernel<<<NBATCH * HNUM * 16, 256, 0, stream>>>(vals, keys, qrs, E, zbuf);
    out_kernel<<<dim3(NBATCH * SDIM / 16, EMBD / 128), 256, 0, stream>>>(zbuf, WoT, bo, out);
}

// Round 2
// 357.119 us; speedup vs baseline: 4.1468x; 4.1468x over previous
//
#include <hip/hip_runtime.h>
#include <hip/hip_bf16.h>

#define SDIM 1024
#define HNUM 8
#define DDIM 64
#define EMBD 512
#define NBATCH 8

static constexpr float SCALE = 0.044194173824159216f; // 1/sqrt(512)

typedef short bf16x8 __attribute__((ext_vector_type(8)));
typedef float f32x4 __attribute__((ext_vector_type(4)));

__device__ __forceinline__ ushort bf16_of(float f) {
    return __builtin_bit_cast(unsigned short, __float2bfloat16(f));
}

// swizzled LDS tile access: tile rows of 64 bf16 = 8 chunks of 16B.
// chunk (row, slot) stored at slot ^ (row&7)  -> bank-conflict-free b128 reads.
__device__ __forceinline__ bf16x8 lds8(const ushort* base, int row, int slot) {
    return *(const bf16x8*)(base + (row * 8 + (slot ^ (row & 7))) * 8);
}
__device__ __forceinline__ void stage64(ushort* dst, const ushort* src, int stride, int t) {
    #pragma unroll
    for (int i = 0; i < 2; ++i) {
        const int c = t + i * 256;                 // chunk 0..511
        const int row = c >> 3, slot = c & 7;
        const float4 v = *(const float4*)(src + row * stride + slot * 8);
        *(float4*)(dst + (row * 8 + (slot ^ (row & 7))) * 8) = v;
    }
}

#define MFMA(a, b, c) __builtin_amdgcn_mfma_f32_16x16x32_bf16(a, b, c, 0, 0, 0)

// ---------------------------------------------------------------------------
// Kernel A: per-head projections -> bf16, h-major layout [n][h][s][d]
// ---------------------------------------------------------------------------
__global__ __launch_bounds__(256) void proj_kernel(
    const float* __restrict__ v, const float* __restrict__ k, const float* __restrict__ q,
    const float* __restrict__ Wv, const float* __restrict__ bv,
    const float* __restrict__ Wk, const float* __restrict__ bk,
    const float* __restrict__ Wq, const float* __restrict__ bq,
    ushort* __restrict__ vals_bf, ushort* __restrict__ keys_bf, ushort* __restrict__ qrs_bf)
{
    __shared__ float xs[3][EMBD];
    __shared__ float Ws[3][DDIM][DDIM + 1];

    const int tok = blockIdx.x;              // n*S + s
    const int n = tok >> 10, s = tok & 1023;
    const int t = threadIdx.x;

    for (int e = t; e < 3 * DDIM * DDIM; e += 256) {
        const int m = e >> 12, r = (e >> 6) & 63, c = e & 63;
        const float* Wm = (m == 0) ? Wv : (m == 1) ? Wk : Wq;
        Ws[m][r][c] = Wm[r * DDIM + c];
    }
    for (int e = t; e < 3 * EMBD; e += 256) {
        const int m = e >> 9, c = e & 511;
        const float* xm = (m == 0) ? v : (m == 1) ? k : q;
        xs[m][c] = xm[tok * EMBD + c];
    }
    __syncthreads();

    const int d = t & 63;
    const int hq = t >> 6;
    for (int m = 0; m < 3; ++m) {
        const float* bm = (m == 0) ? bv : (m == 1) ? bk : bq;
        ushort* om = (m == 0) ? vals_bf : (m == 1) ? keys_bf : qrs_bf;
        for (int hh = hq; hh < HNUM; hh += 4) {
            float acc = bm[d];
            #pragma unroll 8
            for (int dd = 0; dd < DDIM; ++dd)
                acc += xs[m][hh * DDIM + dd] * Ws[m][d][dd];
            om[((n * HNUM + hh) * SDIM + s) * DDIM + d] = bf16_of(acc);
        }
    }
}

// ---------------------------------------------------------------------------
// E -> bf16
// ---------------------------------------------------------------------------
__global__ __launch_bounds__(256) void conv_e(const float* __restrict__ E, ushort* __restrict__ e_bf) {
    const int i = blockIdx.x * 256 + threadIdx.x;  // S*D = 65536
    e_bf[i] = bf16_of(E[i]);
}

// ---------------------------------------------------------------------------
// vals_bf [n][h][s][d] -> valsT_bf [n][h][d][s]  (64x64 tile transpose)
// ---------------------------------------------------------------------------
__global__ __launch_bounds__(256) void transpose_vals(
    const ushort* __restrict__ vals_bf, ushort* __restrict__ valsT_bf)
{
    __shared__ ushort tile[64][72];
    const int blk = blockIdx.x;          // nh*16 + st
    const int st = blk & 15, nh = blk >> 4;
    const int s0 = st * 64;
    const int t = threadIdx.x;
    const ushort* src = vals_bf + (nh * SDIM + s0) * DDIM;
    #pragma unroll
    for (int i = 0; i < 2; ++i) {
        const int c = t + i * 256;
        const int row = c >> 3, slot = c & 7;
        const float4 vv = ((const float4*)src)[c];
        *(float4*)&tile[row][slot * 8] = vv;
    }
    __syncthreads();
    const int d = t >> 2, si = (t & 3) * 16;
    union { ushort u[16]; float4 f[2]; } buf;
    #pragma unroll
    for (int u2 = 0; u2 < 16; ++u2) buf.u[u2] = tile[si + u2][d];
    float4* dst = (float4*)(valsT_bf + (nh * DDIM + d) * SDIM + s0 + si);
    dst[0] = buf.f[0];
    dst[1] = buf.f[1];
}

// ---------------------------------------------------------------------------
// Wo transpose (for coalesced B-reads in out_kernel)
// ---------------------------------------------------------------------------
__global__ __launch_bounds__(256) void transpose_wo(
    const float* __restrict__ Wo, float* __restrict__ WoT)
{
    const int id = blockIdx.x * 256 + threadIdx.x;
    const int kk = id >> 9, c = id & 511;
    WoT[kk * EMBD + c] = Wo[c * EMBD + kk];
}

// ---------------------------------------------------------------------------
// Kernel B: MFMA attention. Block = 4 waves, one 64-row i-tile of one (n,h).
// Per j-tile:
//   jt>=it: S = Q@K^T (MFMA) -> exp/mask -> pe_s;  num += Pexp@V, den += sums
//   jt<=it: band = Vi@Ew^T (MFMA, 64x128), bias(r,c)=band[r][63+c-r] -> pb_s;
//           z2 += Pbias@V
// Row S-1 fully masked -> uniform softmax: z = vsum/S + z2 (vsum via vs_s).
// ---------------------------------------------------------------------------
__global__ __launch_bounds__(256, 2) void attn_mfma(
    const ushort* __restrict__ vals_bf, const ushort* __restrict__ keys_bf,
    const ushort* __restrict__ qrs_bf, const ushort* __restrict__ valsT_bf,
    const ushort* __restrict__ e_bf, float* __restrict__ z)
{
    __shared__ ushort k_s [64 * 64];   // 8 KB each
    __shared__ ushort vt_s[64 * 64];
    __shared__ ushort pe_s[64 * 64];
    __shared__ ushort pb_s[64 * 64];
    __shared__ ushort e_s [128 * 64];  // 16 KB
    __shared__ float  vs_s[64];

    // XCD-aware swizzle: group the 128 blocks of one n per XCD (1024 % 8 == 0)
    const int vid = blockIdx.x;
    const int blk = (vid & 7) * 128 + (vid >> 3);
    const int it = blk & 15, h = (blk >> 4) & 7, n = blk >> 7;
    const int i0 = it * 64;
    const int t = threadIdx.x;
    const int w = t >> 6, l = t & 63;
    const int lrow = l & 15, lgrp = l >> 4;

    const ushort* Qb  = qrs_bf   + (n * HNUM + h) * (SDIM * DDIM);
    const ushort* Kb  = keys_bf  + (n * HNUM + h) * (SDIM * DDIM);
    const ushort* Vb  = vals_bf  + (n * HNUM + h) * (SDIM * DDIM);
    const ushort* VTb = valsT_bf + (n * HNUM + h) * (SDIM * DDIM);

    // A-fragments for Q and Vi: loaded once (wave's 16 rows, k = lgrp*8 + kc*32)
    bf16x8 a_q[2], a_vi[2];
    {
        const int grow = i0 + w * 16 + lrow;
        #pragma unroll
        for (int kc = 0; kc < 2; ++kc) {
            a_q[kc]  = *(const bf16x8*)(Qb + grow * DDIM + kc * 32 + lgrp * 8);
            a_vi[kc] = *(const bf16x8*)(Vb + grow * DDIM + kc * 32 + lgrp * 8);
        }
    }
    if (t < 64) vs_s[t] = 0.f;

    f32x4 accn[4], accz[4];
    #pragma unroll
    for (int f = 0; f < 4; ++f) {
        accn[f] = {0.f, 0.f, 0.f, 0.f};
        accz[f] = {0.f, 0.f, 0.f, 0.f};
    }
    float den[4] = {0.f, 0.f, 0.f, 0.f};

    for (int jt = 0; jt < 16; ++jt) {
        const int j0 = jt * 64;
        const bool diag = (jt == it);
        __syncthreads();  // previous PV done with vt_s/pe_s/pb_s

        // ---- stage ----
        stage64(vt_s, VTb + j0, SDIM, t);            // V^T tile: row d, cols j
        if (jt >= it) stage64(k_s, Kb + j0 * DDIM, DDIM, t);
        if (jt <= it) {                              // E window rows eb..eb+127
            const int eb = SDIM - 64 - i0 + j0;
            #pragma unroll
            for (int i = 0; i < 4; ++i) {
                const int c = t + i * 256;           // chunk 0..1023
                const int row = c >> 3, slot = c & 7;
                const int g = eb + row;
                float4 vv = make_float4(0.f, 0.f, 0.f, 0.f);
                if (g < SDIM) vv = *(const float4*)(e_bf + g * DDIM + slot * 8);
                *(float4*)(e_s + (row * 8 + (slot ^ (row & 7))) * 8) = vv;
            }
        }
        __syncthreads();

        // vsum (only the block containing row S-1 needs it)
        if (it == 15 && t < 64) {
            float s = 0.f;
            #pragma unroll
            for (int slot = 0; slot < 8; ++slot) {
                const bf16x8 vv = lds8(vt_s, t, slot);
                #pragma unroll
                for (int u = 0; u < 8; ++u)
                    s += __bfloat162float(__builtin_bit_cast(__hip_bfloat16, (unsigned short)vv[u]));
            }
            vs_s[t] += s;
        }

        // ---- phase 1: build P tiles ----
        if (jt >= it) {
            f32x4 sf[4];
            #pragma unroll
            for (int fc = 0; fc < 4; ++fc) sf[fc] = {0.f, 0.f, 0.f, 0.f};
            #pragma unroll
            for (int fc = 0; fc < 4; ++fc)
                #pragma unroll
                for (int kc = 0; kc < 2; ++kc)
                    sf[fc] = MFMA(a_q[kc], lds8(k_s, fc * 16 + lrow, lgrp + kc * 4), sf[fc]);
            #pragma unroll
            for (int fc = 0; fc < 4; ++fc) {
                #pragma unroll
                for (int r = 0; r < 4; ++r) {
                    const int row = w * 16 + lgrp * 4 + r;   // local i
                    const int col = fc * 16 + lrow;          // local j
                    float e = 0.f;
                    if (!diag || col > row) e = __expf(sf[fc][r] * SCALE);
                    den[r] += e;
                    pe_s[(row * 8 + ((col >> 3) ^ (row & 7))) * 8 + (col & 7)] = bf16_of(e);
                }
            }
        }
        if (jt <= it) {
            f32x4 bd[8];
            #pragma unroll
            for (int fc = 0; fc < 8; ++fc) bd[fc] = {0.f, 0.f, 0.f, 0.f};
            #pragma unroll
            for (int fc = 0; fc < 4; ++fc)
                #pragma unroll
                for (int kc = 0; kc < 2; ++kc)
                    bd[fc] = MFMA(a_vi[kc], lds8(e_s, fc * 16 + lrow, lgrp + kc * 4), bd[fc]);
            if (!diag) {
                #pragma unroll
                for (int fc = 4; fc < 8; ++fc)
                    #pragma unroll
                    for (int kc = 0; kc < 2; ++kc)
                        bd[fc] = MFMA(a_vi[kc], lds8(e_s, fc * 16 + lrow, lgrp + kc * 4), bd[fc]);
            }
            // extract band -> bias tile: bias(row, c) = band[row][63 + c - row]
            #pragma unroll
            for (int fc = 0; fc < 8; ++fc) {
                #pragma unroll
                for (int r = 0; r < 4; ++r) {
                    const int row = w * 16 + lgrp * 4 + r;
                    const int u = fc * 16 + lrow;
                    const int c = u - 63 + row;
                    if (c >= 0 && c < 64) {
                        const float val = (diag && u > 63) ? 0.f : bd[fc][r];
                        pb_s[(row * 8 + ((c >> 3) ^ (row & 7))) * 8 + (c & 7)] = bf16_of(val);
                    }
                }
            }
        }
        __syncthreads();  // pe_s / pb_s ready

        // ---- phase 2: PV ----
        if (jt >= it) {
            bf16x8 ap[2];
            #pragma unroll
            for (int kc = 0; kc < 2; ++kc) ap[kc] = lds8(pe_s, w * 16 + lrow, lgrp + kc * 4);
            #pragma unroll
            for (int fc = 0; fc < 4; ++fc)
                #pragma unroll
                for (int kc = 0; kc < 2; ++kc)
                    accn[fc] = MFMA(ap[kc], lds8(vt_s, fc * 16 + lrow, lgrp + kc * 4), accn[fc]);
        }
        if (jt <= it) {
            bf16x8 ap[2];
            #pragma unroll
            for (int kc = 0; kc < 2; ++kc) ap[kc] = lds8(pb_s, w * 16 + lrow, lgrp + kc * 4);
            #pragma unroll
            for (int fc = 0; fc < 4; ++fc)
                #pragma unroll
                for (int kc = 0; kc < 2; ++kc)
                    accz[fc] = MFMA(ap[kc], lds8(vt_s, fc * 16 + lrow, lgrp + kc * 4), accz[fc]);
        }
    }

    __syncthreads();  // vs_s visibility

    // den: reduce across the 16 lanes (lrow) holding cols of the same rows
    #pragma unroll
    for (int r = 0; r < 4; ++r) {
        float d = den[r];
        d += __shfl_xor(d, 1);
        d += __shfl_xor(d, 2);
        d += __shfl_xor(d, 4);
        d += __shfl_xor(d, 8);
        den[r] = d;
    }

    #pragma unroll
    for (int fc = 0; fc < 4; ++fc) {
        #pragma unroll
        for (int r = 0; r < 4; ++r) {
            const int grow = i0 + w * 16 + lgrp * 4 + r;
            const int col = fc * 16 + lrow;
            float o;
            if (grow == SDIM - 1)
                o = vs_s[col] * (1.0f / SDIM) + accz[fc][r];
            else
                o = accn[fc][r] / den[r] + accz[fc][r];
            z[(n * SDIM + grow) * EMBD + h * DDIM + col] = o;
        }
    }
}

// ---------------------------------------------------------------------------
// Kernel C: out = z @ Wo.T + bo   (fp32, reads pre-transposed WoT)
// ---------------------------------------------------------------------------
__global__ __launch_bounds__(256) void out_kernel(
    const float* __restrict__ z, const float* __restrict__ WoT,
    const float* __restrict__ bo, float* __restrict__ out)
{
    __shared__ float z_s[16][EMBD];
    const int r0 = blockIdx.x * 16;
    const int c0 = blockIdx.y * 128;
    const int t = threadIdx.x;

    for (int e = t; e < 16 * (EMBD / 4); e += 256) {
        const int row = e >> 7, col4 = e & 127;
        ((float4*)&z_s[row][0])[col4] = ((const float4*)&z[(r0 + row) * EMBD])[col4];
    }
    __syncthreads();

    const int cq = t & 31;
    const int rq = t >> 5;
    const int c = c0 + cq * 4;
    float4 acc0 = make_float4(0.f, 0.f, 0.f, 0.f);
    float4 acc1 = make_float4(0.f, 0.f, 0.f, 0.f);
    for (int kk = 0; kk < EMBD; ++kk) {
        const float4 b = *(const float4*)&WoT[kk * EMBD + c];
        const float a0 = z_s[rq * 2 + 0][kk];
        const float a1 = z_s[rq * 2 + 1][kk];
        acc0.x += a0 * b.x; acc0.y += a0 * b.y; acc0.z += a0 * b.z; acc0.w += a0 * b.w;
        acc1.x += a1 * b.x; acc1.y += a1 * b.y; acc1.z += a1 * b.z; acc1.w += a1 * b.w;
    }
    const float4 bb = *(const float4*)&bo[c];
    acc0.x += bb.x; acc0.y += bb.y; acc0.z += bb.z; acc0.w += bb.w;
    acc1.x += bb.x; acc1.y += bb.y; acc1.z += bb.z; acc1.w += bb.w;
    *(float4*)&out[(r0 + rq * 2 + 0) * EMBD + c] = acc0;
    *(float4*)&out[(r0 + rq * 2 + 1) * EMBD + c] = acc1;
}

// ---------------------------------------------------------------------------
extern "C" void kernel_launch(void* const* d_in, const int* in_sizes, int n_in,
                              void* d_out, int out_size, void* d_ws, size_t ws_size,
                              hipStream_t stream) {
    const float* v  = (const float*)d_in[0];
    const float* k  = (const float*)d_in[1];
    const float* q  = (const float*)d_in[2];
    const float* Wv = (const float*)d_in[3];
    const float* bv = (const float*)d_in[4];
    const float* Wk = (const float*)d_in[5];
    const float* bk = (const float*)d_in[6];
    const float* Wq = (const float*)d_in[7];
    const float* bq = (const float*)d_in[8];
    const float* E  = (const float*)d_in[9];
    const float* Wo = (const float*)d_in[10];
    const float* bo = (const float*)d_in[11];
    float* out = (float*)d_out;

    char* ws = (char*)d_ws;
    ushort* qrs_bf   = (ushort*)(ws);                       // 8 MB
    ushort* keys_bf  = (ushort*)(ws + ((size_t)8 << 20));   // 8 MB
    ushort* vals_bf  = (ushort*)(ws + ((size_t)16 << 20));  // 8 MB
    ushort* valsT_bf = (ushort*)(ws + ((size_t)24 << 20));  // 8 MB
    ushort* e_bf     = (ushort*)(ws + ((size_t)32 << 20));  // 128 KB
    float*  zbuf     = (float*) (ws + ((size_t)33 << 20));  // 16 MB
    float*  WoT      = (float*) (ws + ((size_t)49 << 20));  // 1 MB

    proj_kernel<<<NBATCH * SDIM, 256, 0, stream>>>(v, k, q, Wv, bv, Wk, bk, Wq, bq,
                                                   vals_bf, keys_bf, qrs_bf);
    conv_e<<<(SDIM * DDIM) / 256, 256, 0, stream>>>(E, e_bf);
    transpose_vals<<<NBATCH * HNUM * 16, 256, 0, stream>>>(vals_bf, valsT_bf);
    transpose_wo<<<(EMBD * EMBD) / 256, 256, 0, stream>>>(Wo, WoT);
    attn_mfma<<<NBATCH * HNUM * 16, 256, 0, stream>>>(vals_bf, keys_bf, qrs_bf,
                                                      valsT_bf, e_bf, zbuf);
    out_kernel<<<dim3(NBATCH * SDIM / 16, EMBD / 128), 256, 0, stream>>>(zbuf, WoT, bo, out);
}

// Round 3
// 137.185 us; speedup vs baseline: 10.7948x; 2.6032x over previous
//
#include <hip/hip_runtime.h>
#include <hip/hip_bf16.h>

#define SDIM 1024
#define HNUM 8
#define DDIM 64
#define EMBD 512
#define NBATCH 8

static constexpr float SCALE = 0.044194173824159216f; // 1/sqrt(512)

typedef short bf16x8 __attribute__((ext_vector_type(8)));
typedef float f32x4 __attribute__((ext_vector_type(4)));

__device__ __forceinline__ ushort bf16_of(float f) {
    return __builtin_bit_cast(unsigned short, __float2bfloat16(f));
}
__device__ __forceinline__ float f32_of(ushort u) {
    return __bfloat162float(__builtin_bit_cast(__hip_bfloat16, u));
}

// swizzled LDS tile access: tile rows of 64 bf16 = 8 chunks of 16B.
// chunk (row, slot) stored at slot ^ (row&7)  -> bank-conflict-free b128 reads.
__device__ __forceinline__ bf16x8 lds8(const ushort* base, int row, int slot) {
    return *(const bf16x8*)(base + (row * 8 + (slot ^ (row & 7))) * 8);
}
__device__ __forceinline__ void stage64(ushort* dst, const ushort* src, int stride, int t) {
    #pragma unroll
    for (int i = 0; i < 2; ++i) {
        const int c = t + i * 256;                 // chunk 0..511
        const int row = c >> 3, slot = c & 7;
        const float4 v = *(const float4*)(src + row * stride + slot * 8);
        *(float4*)(dst + (row * 8 + (slot ^ (row & 7))) * 8) = v;
    }
}

#define MFMA(a, b, c) __builtin_amdgcn_mfma_f32_16x16x32_bf16(a, b, c, 0, 0, 0)

// ---------------------------------------------------------------------------
// Kernel A (MFMA): per-head projections -> bf16, h-major layout [n][h][s][d].
// One block = 32 tokens x 8 heads = 256 rows of ONE matrix (m = blk%3).
// out[r][d] = sum_k X[r][k] * W[d][k] + b[d]; B-operand = W rows directly.
// ---------------------------------------------------------------------------
__global__ __launch_bounds__(256) void proj_mfma(
    const float* __restrict__ xv, const float* __restrict__ xk, const float* __restrict__ xq,
    const float* __restrict__ Wv, const float* __restrict__ bv,
    const float* __restrict__ Wk, const float* __restrict__ bk,
    const float* __restrict__ Wq, const float* __restrict__ bq,
    ushort* __restrict__ vals_bf, ushort* __restrict__ keys_bf, ushort* __restrict__ qrs_bf)
{
    __shared__ ushort a_s[256 * 64];   // 32 KB (also reused for C)
    __shared__ ushort w_s[64 * 64];    // 8 KB

    const int blk = blockIdx.x;        // 768 = 3 * 256
    const int m = blk % 3;
    const int chunk = blk / 3;
    const int tok0 = chunk * 32;
    const int n = tok0 >> 10, s0 = tok0 & 1023;
    const int t = threadIdx.x;
    const int w = t >> 6, l = t & 63, lrow = l & 15, lgrp = l >> 4;

    const float* X = (m == 0) ? xv : (m == 1) ? xk : xq;
    const float* W = (m == 0) ? Wv : (m == 1) ? Wk : Wq;
    const float* B = (m == 0) ? bv : (m == 1) ? bk : bq;
    ushort* O = (m == 0) ? vals_bf : (m == 1) ? keys_bf : qrs_bf;

    // stage A: 32 tokens x 512 floats, coalesced float4, rows r = h*32 + ls
    #pragma unroll
    for (int i = 0; i < 16; ++i) {
        const int f4 = i * 256 + t;            // 0..4095
        const int ls = f4 >> 7, c4 = f4 & 127;
        const int h = c4 >> 4, d4 = c4 & 15;
        const float4 v = ((const float4*)(X + (size_t)(tok0 + ls) * EMBD))[c4];
        ushort4 u;
        u.x = bf16_of(v.x); u.y = bf16_of(v.y); u.z = bf16_of(v.z); u.w = bf16_of(v.w);
        const int r = h * 32 + ls, slot = d4 >> 1;
        *(ushort4*)(a_s + (r * 8 + (slot ^ (r & 7))) * 8 + (d4 & 1) * 4) = u;
    }
    // stage W (64x64 fp32 -> bf16)
    #pragma unroll
    for (int i = 0; i < 4; ++i) {
        const int f4 = i * 256 + t;            // 0..1023
        const int r = f4 >> 4, d4 = f4 & 15;
        const float4 v = ((const float4*)W)[f4];
        ushort4 u;
        u.x = bf16_of(v.x); u.y = bf16_of(v.y); u.z = bf16_of(v.z); u.w = bf16_of(v.w);
        const int slot = d4 >> 1;
        *(ushort4*)(w_s + (r * 8 + (slot ^ (r & 7))) * 8 + (d4 & 1) * 4) = u;
    }
    __syncthreads();

    f32x4 acc[4][4];
    #pragma unroll
    for (int fr = 0; fr < 4; ++fr)
        #pragma unroll
        for (int fc = 0; fc < 4; ++fc) acc[fr][fc] = {0.f, 0.f, 0.f, 0.f};

    bf16x8 af[4][2];
    #pragma unroll
    for (int fr = 0; fr < 4; ++fr)
        #pragma unroll
        for (int kc = 0; kc < 2; ++kc)
            af[fr][kc] = lds8(a_s, w * 64 + fr * 16 + lrow, lgrp + kc * 4);

    #pragma unroll
    for (int fc = 0; fc < 4; ++fc)
        #pragma unroll
        for (int kc = 0; kc < 2; ++kc) {
            const bf16x8 bfr = lds8(w_s, fc * 16 + lrow, lgrp + kc * 4);
            #pragma unroll
            for (int fr = 0; fr < 4; ++fr)
                acc[fr][fc] = MFMA(af[fr][kc], bfr, acc[fr][fc]);
        }
    __syncthreads();

    // C (+bias) -> a_s as bf16
    float bias[4];
    #pragma unroll
    for (int fc = 0; fc < 4; ++fc) bias[fc] = B[fc * 16 + lrow];
    #pragma unroll
    for (int fr = 0; fr < 4; ++fr)
        #pragma unroll
        for (int fc = 0; fc < 4; ++fc)
            #pragma unroll
            for (int reg = 0; reg < 4; ++reg) {
                const int row = w * 64 + fr * 16 + lgrp * 4 + reg;
                const int col = fc * 16 + lrow;
                a_s[(row * 8 + ((col >> 3) ^ (row & 7))) * 8 + (col & 7)] =
                    bf16_of(acc[fr][fc][reg] + bias[fc]);
            }
    __syncthreads();

    // coalesced write-out of head panels
    #pragma unroll
    for (int i = 0; i < 8; ++i) {
        const int cc = i * 256 + t;            // 0..2047
        const int r = cc >> 3, slot = cc & 7;
        const int h = r >> 5, ls = r & 31;
        const float4 v = *(const float4*)(a_s + (r * 8 + (slot ^ (r & 7))) * 8);
        *(float4*)(O + ((size_t)(n * HNUM + h) * SDIM + s0 + ls) * DDIM + slot * 8) = v;
    }
}

// ---------------------------------------------------------------------------
// E -> bf16 ;  Wo -> bf16 (row-major [c][k] == MFMA B-operand layout)
// ---------------------------------------------------------------------------
__global__ __launch_bounds__(256) void conv_e(const float* __restrict__ E, ushort* __restrict__ e_bf) {
    const int i = blockIdx.x * 256 + threadIdx.x;
    e_bf[i] = bf16_of(E[i]);
}
__global__ __launch_bounds__(256) void conv_wo(const float* __restrict__ Wo, ushort* __restrict__ wo_bf) {
    const int i = blockIdx.x * 256 + threadIdx.x;
    wo_bf[i] = bf16_of(Wo[i]);
}

// ---------------------------------------------------------------------------
// vals_bf [n][h][s][d] -> valsT_bf [n][h][d][s]  (64x64 tile transpose)
// ---------------------------------------------------------------------------
__global__ __launch_bounds__(256) void transpose_vals(
    const ushort* __restrict__ vals_bf, ushort* __restrict__ valsT_bf)
{
    __shared__ ushort tile[64][72];
    const int blk = blockIdx.x;
    const int st = blk & 15, nh = blk >> 4;
    const int s0 = st * 64;
    const int t = threadIdx.x;
    const ushort* src = vals_bf + (nh * SDIM + s0) * DDIM;
    #pragma unroll
    for (int i = 0; i < 2; ++i) {
        const int c = t + i * 256;
        const int row = c >> 3, slot = c & 7;
        const float4 vv = ((const float4*)src)[c];
        *(float4*)&tile[row][slot * 8] = vv;
    }
    __syncthreads();
    const int d = t >> 2, si = (t & 3) * 16;
    union { ushort u[16]; float4 f[2]; } buf;
    #pragma unroll
    for (int u2 = 0; u2 < 16; ++u2) buf.u[u2] = tile[si + u2][d];
    float4* dst = (float4*)(valsT_bf + (nh * DDIM + d) * SDIM + s0 + si);
    dst[0] = buf.f[0];
    dst[1] = buf.f[1];
}

// ---------------------------------------------------------------------------
// Kernel B: MFMA attention (unchanged math; epilogue now emits z as bf16 hi+lo)
// ---------------------------------------------------------------------------
__global__ __launch_bounds__(256, 2) void attn_mfma(
    const ushort* __restrict__ vals_bf, const ushort* __restrict__ keys_bf,
    const ushort* __restrict__ qrs_bf, const ushort* __restrict__ valsT_bf,
    const ushort* __restrict__ e_bf,
    ushort* __restrict__ zh, ushort* __restrict__ zl)
{
    __shared__ ushort k_s [64 * 64];
    __shared__ ushort vt_s[64 * 64];
    __shared__ ushort pe_s[64 * 64];
    __shared__ ushort pb_s[64 * 64];
    __shared__ ushort e_s [128 * 64];
    __shared__ float  vs_s[64];

    const int vid = blockIdx.x;
    const int blk = (vid & 7) * 128 + (vid >> 3);
    const int it = blk & 15, h = (blk >> 4) & 7, n = blk >> 7;
    const int i0 = it * 64;
    const int t = threadIdx.x;
    const int w = t >> 6, l = t & 63;
    const int lrow = l & 15, lgrp = l >> 4;

    const ushort* Qb  = qrs_bf   + (n * HNUM + h) * (SDIM * DDIM);
    const ushort* Kb  = keys_bf  + (n * HNUM + h) * (SDIM * DDIM);
    const ushort* Vb  = vals_bf  + (n * HNUM + h) * (SDIM * DDIM);
    const ushort* VTb = valsT_bf + (n * HNUM + h) * (SDIM * DDIM);

    bf16x8 a_q[2], a_vi[2];
    {
        const int grow = i0 + w * 16 + lrow;
        #pragma unroll
        for (int kc = 0; kc < 2; ++kc) {
            a_q[kc]  = *(const bf16x8*)(Qb + grow * DDIM + kc * 32 + lgrp * 8);
            a_vi[kc] = *(const bf16x8*)(Vb + grow * DDIM + kc * 32 + lgrp * 8);
        }
    }
    if (t < 64) vs_s[t] = 0.f;

    f32x4 accn[4], accz[4];
    #pragma unroll
    for (int f = 0; f < 4; ++f) {
        accn[f] = {0.f, 0.f, 0.f, 0.f};
        accz[f] = {0.f, 0.f, 0.f, 0.f};
    }
    float den[4] = {0.f, 0.f, 0.f, 0.f};

    for (int jt = 0; jt < 16; ++jt) {
        const int j0 = jt * 64;
        const bool diag = (jt == it);
        __syncthreads();

        stage64(vt_s, VTb + j0, SDIM, t);
        if (jt >= it) stage64(k_s, Kb + j0 * DDIM, DDIM, t);
        if (jt <= it) {
            const int eb = SDIM - 64 - i0 + j0;
            #pragma unroll
            for (int i = 0; i < 4; ++i) {
                const int c = t + i * 256;
                const int row = c >> 3, slot = c & 7;
                const int g = eb + row;
                float4 vv = make_float4(0.f, 0.f, 0.f, 0.f);
                if (g < SDIM) vv = *(const float4*)(e_bf + g * DDIM + slot * 8);
                *(float4*)(e_s + (row * 8 + (slot ^ (row & 7))) * 8) = vv;
            }
        }
        __syncthreads();

        if (it == 15 && t < 64) {
            float s = 0.f;
            #pragma unroll
            for (int slot = 0; slot < 8; ++slot) {
                const bf16x8 vv = lds8(vt_s, t, slot);
                #pragma unroll
                for (int u = 0; u < 8; ++u) s += f32_of((ushort)vv[u]);
            }
            vs_s[t] += s;
        }

        if (jt >= it) {
            f32x4 sf[4];
            #pragma unroll
            for (int fc = 0; fc < 4; ++fc) sf[fc] = {0.f, 0.f, 0.f, 0.f};
            #pragma unroll
            for (int fc = 0; fc < 4; ++fc)
                #pragma unroll
                for (int kc = 0; kc < 2; ++kc)
                    sf[fc] = MFMA(a_q[kc], lds8(k_s, fc * 16 + lrow, lgrp + kc * 4), sf[fc]);
            #pragma unroll
            for (int fc = 0; fc < 4; ++fc) {
                #pragma unroll
                for (int r = 0; r < 4; ++r) {
                    const int row = w * 16 + lgrp * 4 + r;
                    const int col = fc * 16 + lrow;
                    float e = 0.f;
                    if (!diag || col > row) e = __expf(sf[fc][r] * SCALE);
                    den[r] += e;
                    pe_s[(row * 8 + ((col >> 3) ^ (row & 7))) * 8 + (col & 7)] = bf16_of(e);
                }
            }
        }
        if (jt <= it) {
            f32x4 bd[8];
            #pragma unroll
            for (int fc = 0; fc < 8; ++fc) bd[fc] = {0.f, 0.f, 0.f, 0.f};
            #pragma unroll
            for (int fc = 0; fc < 4; ++fc)
                #pragma unroll
                for (int kc = 0; kc < 2; ++kc)
                    bd[fc] = MFMA(a_vi[kc], lds8(e_s, fc * 16 + lrow, lgrp + kc * 4), bd[fc]);
            if (!diag) {
                #pragma unroll
                for (int fc = 4; fc < 8; ++fc)
                    #pragma unroll
                    for (int kc = 0; kc < 2; ++kc)
                        bd[fc] = MFMA(a_vi[kc], lds8(e_s, fc * 16 + lrow, lgrp + kc * 4), bd[fc]);
            }
            #pragma unroll
            for (int fc = 0; fc < 8; ++fc) {
                #pragma unroll
                for (int r = 0; r < 4; ++r) {
                    const int row = w * 16 + lgrp * 4 + r;
                    const int u = fc * 16 + lrow;
                    const int c = u - 63 + row;
                    if (c >= 0 && c < 64) {
                        const float val = (diag && u > 63) ? 0.f : bd[fc][r];
                        pb_s[(row * 8 + ((c >> 3) ^ (row & 7))) * 8 + (c & 7)] = bf16_of(val);
                    }
                }
            }
        }
        __syncthreads();

        if (jt >= it) {
            bf16x8 ap[2];
            #pragma unroll
            for (int kc = 0; kc < 2; ++kc) ap[kc] = lds8(pe_s, w * 16 + lrow, lgrp + kc * 4);
            #pragma unroll
            for (int fc = 0; fc < 4; ++fc)
                #pragma unroll
                for (int kc = 0; kc < 2; ++kc)
                    accn[fc] = MFMA(ap[kc], lds8(vt_s, fc * 16 + lrow, lgrp + kc * 4), accn[fc]);
        }
        if (jt <= it) {
            bf16x8 ap[2];
            #pragma unroll
            for (int kc = 0; kc < 2; ++kc) ap[kc] = lds8(pb_s, w * 16 + lrow, lgrp + kc * 4);
            #pragma unroll
            for (int fc = 0; fc < 4; ++fc)
                #pragma unroll
                for (int kc = 0; kc < 2; ++kc)
                    accz[fc] = MFMA(ap[kc], lds8(vt_s, fc * 16 + lrow, lgrp + kc * 4), accz[fc]);
        }
    }

    __syncthreads();

    #pragma unroll
    for (int r = 0; r < 4; ++r) {
        float d = den[r];
        d += __shfl_xor(d, 1);
        d += __shfl_xor(d, 2);
        d += __shfl_xor(d, 4);
        d += __shfl_xor(d, 8);
        den[r] = d;
    }

    #pragma unroll
    for (int fc = 0; fc < 4; ++fc) {
        #pragma unroll
        for (int r = 0; r < 4; ++r) {
            const int grow = i0 + w * 16 + lgrp * 4 + r;
            const int col = fc * 16 + lrow;
            float o;
            if (grow == SDIM - 1)
                o = vs_s[col] * (1.0f / SDIM) + accz[fc][r];
            else
                o = accn[fc][r] / den[r] + accz[fc][r];
            const size_t idx = (size_t)(n * SDIM + grow) * EMBD + h * DDIM + col;
            const ushort hi = bf16_of(o);
            zh[idx] = hi;
            zl[idx] = bf16_of(o - f32_of(hi));
        }
    }
}

// ---------------------------------------------------------------------------
// Kernel C (MFMA): out = (zh + zl) @ Wo.T + bo.  128x64 tiles, K=512.
// B-operand = wo_bf rows ([c][k] layout). XCD swizzle groups A-sharing blocks.
// ---------------------------------------------------------------------------
__global__ __launch_bounds__(256) void out_mfma(
    const ushort* __restrict__ zh, const ushort* __restrict__ zl,
    const ushort* __restrict__ wo_bf, const float* __restrict__ bo,
    float* __restrict__ out)
{
    __shared__ ushort ah_s[128 * 64];  // 16 KB
    __shared__ ushort al_s[128 * 64];  // 16 KB
    __shared__ ushort b_s [64 * 64];   // 8 KB

    const int vid = blockIdx.x;                 // 512 blocks
    const int blk = (vid & 7) * 64 + (vid >> 3);
    const int r0 = (blk >> 3) * 128, c0 = (blk & 7) * 64;
    const int t = threadIdx.x;
    const int w = t >> 6, l = t & 63, lrow = l & 15, lgrp = l >> 4;

    f32x4 acc[2][4];
    #pragma unroll
    for (int fr = 0; fr < 2; ++fr)
        #pragma unroll
        for (int fc = 0; fc < 4; ++fc) acc[fr][fc] = {0.f, 0.f, 0.f, 0.f};

    for (int kt = 0; kt < 8; ++kt) {
        __syncthreads();
        #pragma unroll
        for (int i = 0; i < 4; ++i) {
            const int cc = i * 256 + t;         // 0..1023
            const int r = cc >> 3, slot = cc & 7;
            const size_t src = (size_t)(r0 + r) * EMBD + kt * 64 + slot * 8;
            const float4 vh = *(const float4*)(zh + src);
            const float4 vl = *(const float4*)(zl + src);
            *(float4*)(ah_s + (r * 8 + (slot ^ (r & 7))) * 8) = vh;
            *(float4*)(al_s + (r * 8 + (slot ^ (r & 7))) * 8) = vl;
        }
        #pragma unroll
        for (int i = 0; i < 2; ++i) {
            const int cc = i * 256 + t;         // 0..511
            const int r = cc >> 3, slot = cc & 7;
            const float4 vb = *(const float4*)(wo_bf + (size_t)(c0 + r) * EMBD + kt * 64 + slot * 8);
            *(float4*)(b_s + (r * 8 + (slot ^ (r & 7))) * 8) = vb;
        }
        __syncthreads();

        #pragma unroll
        for (int kc = 0; kc < 2; ++kc)
            #pragma unroll
            for (int fc = 0; fc < 4; ++fc) {
                const bf16x8 bfr = lds8(b_s, fc * 16 + lrow, lgrp + kc * 4);
                #pragma unroll
                for (int fr = 0; fr < 2; ++fr) {
                    acc[fr][fc] = MFMA(lds8(ah_s, w * 32 + fr * 16 + lrow, lgrp + kc * 4), bfr, acc[fr][fc]);
                    acc[fr][fc] = MFMA(lds8(al_s, w * 32 + fr * 16 + lrow, lgrp + kc * 4), bfr, acc[fr][fc]);
                }
            }
    }

    float bias[4];
    #pragma unroll
    for (int fc = 0; fc < 4; ++fc) bias[fc] = bo[c0 + fc * 16 + lrow];
    #pragma unroll
    for (int fr = 0; fr < 2; ++fr)
        #pragma unroll
        for (int fc = 0; fc < 4; ++fc)
            #pragma unroll
            for (int reg = 0; reg < 4; ++reg) {
                const int row = r0 + w * 32 + fr * 16 + lgrp * 4 + reg;
                const int col = c0 + fc * 16 + lrow;
                out[(size_t)row * EMBD + col] = acc[fr][fc][reg] + bias[fc];
            }
}

// ---------------------------------------------------------------------------
extern "C" void kernel_launch(void* const* d_in, const int* in_sizes, int n_in,
                              void* d_out, int out_size, void* d_ws, size_t ws_size,
                              hipStream_t stream) {
    const float* v  = (const float*)d_in[0];
    const float* k  = (const float*)d_in[1];
    const float* q  = (const float*)d_in[2];
    const float* Wv = (const float*)d_in[3];
    const float* bv = (const float*)d_in[4];
    const float* Wk = (const float*)d_in[5];
    const float* bk = (const float*)d_in[6];
    const float* Wq = (const float*)d_in[7];
    const float* bq = (const float*)d_in[8];
    const float* E  = (const float*)d_in[9];
    const float* Wo = (const float*)d_in[10];
    const float* bo = (const float*)d_in[11];
    float* out = (float*)d_out;

    char* ws = (char*)d_ws;
    ushort* qrs_bf   = (ushort*)(ws);                       // 8 MB
    ushort* keys_bf  = (ushort*)(ws + ((size_t)8 << 20));   // 8 MB
    ushort* vals_bf  = (ushort*)(ws + ((size_t)16 << 20));  // 8 MB
    ushort* valsT_bf = (ushort*)(ws + ((size_t)24 << 20));  // 8 MB
    ushort* e_bf     = (ushort*)(ws + ((size_t)32 << 20));  // 128 KB
    ushort* wo_bf    = (ushort*)(ws + ((size_t)33 << 20));  // 512 KB
    ushort* zh       = (ushort*)(ws + ((size_t)34 << 20));  // 8 MB
    ushort* zl       = (ushort*)(ws + ((size_t)42 << 20));  // 8 MB

    proj_mfma<<<768, 256, 0, stream>>>(v, k, q, Wv, bv, Wk, bk, Wq, bq,
                                       vals_bf, keys_bf, qrs_bf);
    conv_e<<<(SDIM * DDIM) / 256, 256, 0, stream>>>(E, e_bf);
    conv_wo<<<(EMBD * EMBD) / 256, 256, 0, stream>>>(Wo, wo_bf);
    transpose_vals<<<NBATCH * HNUM * 16, 256, 0, stream>>>(vals_bf, valsT_bf);
    attn_mfma<<<NBATCH * HNUM * 16, 256, 0, stream>>>(vals_bf, keys_bf, qrs_bf,
                                                      valsT_bf, e_bf, zh, zl);
    out_mfma<<<512, 256, 0, stream>>>(zh, zl, wo_bf, bo, out);
}